// Round 10
// baseline (135.316 us; speedup 1.0000x reference)
//
#include <hip/hip_runtime.h>
#include <math.h>
#include <limits.h>

// Fixed geometry from reference: T=8192, H=512, MC=MD=4096, N_ENT=128,
// MAX_DIST=600, feature dim 100 (padded to 112 for MFMA n-tiles).
#define H_DIM  512
#define NFEAT  100
#define NPAD   112
#define NT     7      // NPAD/16 n-tiles
#define KW     4      // K-split waves in gemm_feat (each wave: 4 of 16 ks)
#define SROW   520    // padded LDS row stride (shorts): 1040B = odd*16B -> 2-way banks
#define MAXD   600
#define MAXE   2048   // sort fast-path entity-count limit
#define SB     16     // sort blocks per side (parallel counting sort)
#define CHK    64     // dis mentions per staged chunk in pair kernel
#define DCH    32     // grid.y: 512 blocks, 2 chunks each (amortize startup)

#define NEG_ENC 0x007FFFFFu  // enc_f(-inf)

typedef __attribute__((ext_vector_type(8))) short short8v;  // 8 bf16
typedef __attribute__((ext_vector_type(4))) float f32x4;

// Monotonic float->uint mapping so unsigned atomicMax == float max.
__device__ __forceinline__ unsigned enc_f(float f){
    unsigned u = __float_as_uint(f);
    return (u & 0x80000000u) ? ~u : (u | 0x80000000u);
}
__device__ __forceinline__ float dec_f(unsigned e){
    unsigned u = (e & 0x80000000u) ? (e ^ 0x80000000u) : ~e;
    return __uint_as_float(u);
}
__device__ __forceinline__ unsigned short f2bf(float f){  // round-nearest-even
    unsigned x = __float_as_uint(f);
    return (unsigned short)((x + 0x7fffu + ((x >> 16) & 1u)) >> 16);
}

// Fused prep, block roles by blockIdx.x:
//  [0, 32)            : per-chunk entity histograms -> ghist (16 blocks/side)
//  [32, off_e)        : gent init to -inf
//  [off_e, off_w)     : emb2[d] = Wemb[d,:]@Ws[200:250] + bs
//  [off_w, ...)       : Wt[side][n][k] = bf16(W_side[k][n])  (zero-pad n>=100)
__global__ __launch_bounds__(256) void prep_kernel(
    const float* __restrict__ Wemb, const float* __restrict__ Ws,
    const float* __restrict__ bs,
    const float* __restrict__ Wc,   const float* __restrict__ Wd,
    const int* __restrict__ cent, const int* __restrict__ dent,
    const int* __restrict__ ncp,  const int* __restrict__ ndp,
    float* __restrict__ emb2, unsigned* __restrict__ gent, int gent_n,
    unsigned short* __restrict__ Wt, int* __restrict__ ghist,
    int MCv, int MDv, int off_e, int off_w)
{
    const int tid = threadIdx.x;
    const int bid = blockIdx.x;

    if (bid < 32){
        __shared__ int hist[MAXE];
        const int side = bid >> 4;
        const int b    = bid & 15;
        const int ne   = side ? *ndp : *ncp;
        if (ne > MAXE) return;                 // fallback: no sort
        const int* ent = side ? dent : cent;
        const int  M   = side ? MDv : MCv;
        const int chunk = (M + SB - 1) / SB;
        const int i0 = b * chunk, i1 = min(M, i0 + chunk);
        for (int e = tid; e < ne; e += 256) hist[e] = 0;
        __syncthreads();
        for (int i = i0 + tid; i < i1; i += 256) atomicAdd(&hist[ent[i]], 1);
        __syncthreads();
        int* gh = ghist + (side*SB + b) * MAXE;
        for (int e = tid; e < ne; e += 256) gh[e] = hist[e];
    } else if (bid < off_e){
        int i = (bid - 32) * 256 + tid;
        if (i < gent_n) gent[i] = NEG_ENC;
    } else if (bid < off_w){
        int d = (bid - off_e) * 256 + tid;
        if (d < MAXD){
            float a0 = bs[0], a1 = bs[1];
            #pragma unroll 5
            for (int q = 0; q < 50; ++q){
                float w = Wemb[d*50 + q];
                a0 += w * Ws[(200+q)*2 + 0];
                a1 += w * Ws[(200+q)*2 + 1];
            }
            emb2[d*2 + 0] = a0;
            emb2[d*2 + 1] = a1;
        }
    } else {
        const int base = (bid - off_w) * 4096;
        #pragma unroll
        for (int ii = 0; ii < 16; ++ii){
            int e = base + tid + 256*ii;
            if (e < 2*NPAD*H_DIM){
                int side = e / (NPAD*H_DIM);
                int rem  = e - side*(NPAD*H_DIM);
                int n    = rem / H_DIM;
                int k    = rem - n*H_DIM;
                const float* W = side ? Wd : Wc;
                Wt[e] = (n < NFEAT) ? f2bf(W[k*NFEAT + n]) : (unsigned short)0;
            }
        }
    }
}

// Blocks [0, mtc+mtd): fused span-sum (h -> LDS, wave-uniform len switch) +
// MFMA GEMM (A from LDS, 4-way K-split) + feature epilogue -> sc[m,2].
// Blocks [mtc+mtd, +32): scatter phase of the parallel counting sort.
__global__ __launch_bounds__(256) void gemm_feat(
    const float* __restrict__ h,
    const unsigned short* __restrict__ Wt,
    const float* __restrict__ bc, const float* __restrict__ bd,
    const float* __restrict__ Ws,
    float* __restrict__ sc_c, float* __restrict__ sc_d,
    const int* __restrict__ cent, const int* __restrict__ dent,
    const int* __restrict__ ncp,  const int* __restrict__ ndp,
    const int* __restrict__ cspans, const int* __restrict__ dspans,
    const int* __restrict__ ghist,
    int4* __restrict__ csorted, int4* __restrict__ dsorted,
    int mtc, int mtd, int MCv, int MDv)
{
    // shared overlay: gemm role = S_lds(16640B) + s_acc(21504B) = 38144B
    //                 scatter role = s_tot(8192) + s_cur(8192) + s_wsum(16)
    __shared__ __align__(16) char smem[38160];
    unsigned short* S_lds = (unsigned short*)smem;
    float*          s_acc = (float*)(smem + 16640);   // [(w-1)*28 + nt*4+r][64]
    int*            s_tot = (int*)smem;
    int*            s_cur = (int*)(smem + 8192);
    int*            s_wsum= (int*)(smem + 16384);

    const int tid  = threadIdx.x;
    const int lane = tid & 63;
    const int w    = tid >> 6;
    const int bid  = blockIdx.x;

    if (bid >= mtc + mtd){
        // ---- scatter role ----
        const int sb   = bid - (mtc + mtd);   // 0..31
        const int side = sb >> 4;
        const int b    = sb & 15;
        const int ne   = side ? *ndp : *ncp;
        const int* ent = side ? dent : cent;
        const int* spans = side ? dspans : cspans;
        int4* out      = side ? dsorted : csorted;
        const int M    = side ? MDv : MCv;
        const int chunk = (M + SB - 1) / SB;
        const int i0 = b * chunk, i1 = min(M, i0 + chunk);

        if (ne <= MAXE){
            const int* gh = ghist + side*SB*MAXE;
            for (int e = tid; e < ne; e += 256){
                int pre = 0, tot = 0;
                #pragma unroll
                for (int bb = 0; bb < SB; ++bb){
                    int v = gh[bb*MAXE + e];
                    tot += v;
                    pre += (bb < b) ? v : 0;
                }
                s_tot[e] = tot;
                s_cur[e] = pre;
            }
            __syncthreads();
            const int per = (ne + 255) / 256;
            const int lo = min(tid*per, ne), hi = min(lo + per, ne);
            int sum = 0;
            for (int j = lo; j < hi; ++j) sum += s_tot[j];
            int x = sum;
            #pragma unroll
            for (int k = 1; k < 64; k <<= 1){
                int y = __shfl_up(x, k);
                if (lane >= k) x += y;
            }
            int excl = x - sum;
            if (lane == 63) s_wsum[w] = x;
            __syncthreads();
            for (int ww = 0; ww < w; ++ww) excl += s_wsum[ww];
            int run = excl;
            for (int j = lo; j < hi; ++j){
                s_cur[j] += run;
                run += s_tot[j];
            }
            __syncthreads();
            for (int i = i0 + tid; i < i1; i += 256){
                int e = ent[i];
                int pos = atomicAdd(&s_cur[e], 1);
                out[pos] = make_int4(spans[i*2], e, i, 0);
            }
        } else {
            for (int i = i0 + tid; i < i1; i += 256)
                out[i] = make_int4(spans[i*2], ent[i], i, 0);
        }
        return;
    }

    // ---- span-sum staging + GEMM + fused feature epilogue ----
    const int side = (bid >= mtc);
    const int mt   = side ? (bid - mtc) : bid;
    const int* spans = side ? dspans : cspans;
    const int  M     = side ? MDv : MCv;

    // stage 4 rows per wave; each row: 64 lanes x 8 floats, len+1 row loads.
    // len is wave-uniform (one row per wave) -> switch costs no divergence.
    #pragma unroll
    for (int rr = 0; rr < 4; ++rr){
        const int rloc = w*4 + rr;            // 0..15
        const int ml   = mt*16 + rloc;
        float A0=0.f,A1=0.f,A2=0.f,A3=0.f,A4=0.f,A5=0.f,A6=0.f,A7=0.f;
        if (ml < M){
            const int s   = spans[ml*2];
            const int len = spans[ml*2 + 1] - s;   // 0..7
            const float* hp = h + (size_t)s * H_DIM + lane*8;
#define RW(r) { const float4* p_ = (const float4*)(hp + (size_t)(r)*H_DIM); \
                float4 u0=p_[0], u1=p_[1]; \
                A0+=u0.x; A1+=u0.y; A2+=u0.z; A3+=u0.w; \
                A4+=u1.x; A5+=u1.y; A6+=u1.z; A7+=u1.w; }
            switch(len){
                case 7: RW(7);
                case 6: RW(6);
                case 5: RW(5);
                case 4: RW(4);
                case 3: RW(3);
                case 2: RW(2);
                case 1: RW(1);
                default: RW(0);
            }
#undef RW
        }
        union { unsigned short us[8]; uint4 v; } o;
        o.us[0]=f2bf(A0); o.us[1]=f2bf(A1); o.us[2]=f2bf(A2); o.us[3]=f2bf(A3);
        o.us[4]=f2bf(A4); o.us[5]=f2bf(A5); o.us[6]=f2bf(A6); o.us[7]=f2bf(A7);
        *reinterpret_cast<uint4*>(S_lds + rloc*SROW + lane*8) = o.v;
    }
    __syncthreads();

    const unsigned short* B = Wt + (size_t)side * NPAD * H_DIM
                                 + (size_t)(lane & 15) * H_DIM
                                 + (lane >> 4) * 8 + w * 4 * 32;
    const unsigned short* Al = S_lds + (lane & 15) * SROW
                                     + (lane >> 4) * 8 + w * 4 * 32;

    f32x4 acc[NT];
    #pragma unroll
    for (int nt = 0; nt < NT; ++nt) acc[nt] = (f32x4){0.f,0.f,0.f,0.f};

    #pragma unroll
    for (int ks = 0; ks < 4; ++ks){
        short8v a = *reinterpret_cast<const short8v*>(Al + ks*32);
        #pragma unroll
        for (int nt = 0; nt < NT; ++nt){
            short8v b = *reinterpret_cast<const short8v*>(B + (size_t)nt*16*H_DIM + ks*32);
            acc[nt] = __builtin_amdgcn_mfma_f32_16x16x32_bf16(a, b, acc[nt], 0, 0, 0);
        }
    }

    if (w > 0){
        #pragma unroll
        for (int nt = 0; nt < NT; ++nt)
            #pragma unroll
            for (int r = 0; r < 4; ++r)
                s_acc[((w-1)*28 + nt*4 + r)*64 + lane] = acc[nt][r];
    }
    __syncthreads();
    if (w == 0){
        #pragma unroll
        for (int nt = 0; nt < NT; ++nt)
            #pragma unroll
            for (int r = 0; r < 4; ++r)
                acc[nt][r] += s_acc[(nt*4+r)*64 + lane]
                            + s_acc[(28 + nt*4+r)*64 + lane]
                            + s_acc[(56 + nt*4+r)*64 + lane];

        const float* bvec = side ? bd : bc;
        const int    wsoff = side ? NFEAT : 0;
        const int    nb    = lane & 15;
        float bb[NT], w0[NT], w1[NT];
        #pragma unroll
        for (int nt = 0; nt < NT; ++nt){
            int n = nt*16 + nb;
            bool v = (n < NFEAT);
            bb[nt] = v ? bvec[n] : 0.f;
            w0[nt] = v ? Ws[(wsoff + n)*2 + 0] : 0.f;
            w1[nt] = v ? Ws[(wsoff + n)*2 + 1] : 0.f;
        }
        const int ml0 = mt*16 + (lane >> 4)*4;
        float* sc     = side ? sc_d : sc_c;
        #pragma unroll
        for (int r = 0; r < 4; ++r){
            float p0 = 0.f, p1 = 0.f;
            #pragma unroll
            for (int nt = 0; nt < NT; ++nt){
                float f = tanhf(acc[nt][r] + bb[nt]);
                p0 += f * w0[nt];
                p1 += f * w1[nt];
            }
            #pragma unroll
            for (int k = 1; k < 16; k <<= 1){
                p0 += __shfl_xor(p0, k);
                p1 += __shfl_xor(p1, k);
            }
            int ml = ml0 + r;
            if (nb == 0 && ml < M){
                sc[ml*2 + 0] = p0;
                sc[ml*2 + 1] = p1;
            }
        }
    }
}

// Segmented (by ce, contiguous after sort) suffix max-reduce + head atomics.
__device__ __forceinline__ void flush_run(
    float s0, float s1, int ce, int de, int nd, bool head,
    const bool okk[6], unsigned* __restrict__ gent)
{
    float a0 = s0, a1 = s1;
    #pragma unroll
    for (int k = 0; k < 6; ++k){
        float b0 = __shfl_down(a0, 1 << k);
        float b1 = __shfl_down(a1, 1 << k);
        if (okk[k]){ a0 = fmaxf(a0, b0); a1 = fmaxf(a1, b1); }
    }
    if (head && ce != INT_MAX){
        atomicMax(&gent[(ce*nd + de)*2 + 0], enc_f(a0));
        atomicMax(&gent[(ce*nd + de)*2 + 1], enc_f(a1));
    }
}

// 256 sorted chem mentions per block (one per lane); stream sorted dis
// mentions in staged chunks (2 chunks/block at DCH=32); per-lane running max
// per dis-entity run; boundary flush via wave-segmented reduce.
// NOTE: no end-of-kernel fence/counter fusion — device-scope __threadfence()
// per block forced an L2 writeback per block on gfx950 (non-coherent per-XCD
// L2s) and regressed pair 42 -> 91 us in R7. The kernel boundary before
// softmax_kernel provides ordering for free.
__global__ __launch_bounds__(256) void pair_kernel(
    const int4* __restrict__ csorted, const int4* __restrict__ dsorted,
    const float* __restrict__ sc_c,   const float* __restrict__ sc_d,
    const float* __restrict__ emb2,   const int* __restrict__ ndp,
    unsigned* __restrict__ gent, int MCv, int MDv)
{
    __shared__ float2 s_e[MAXD];
    __shared__ int4   s_d[CHK];

    const int tid  = threadIdx.x;
    const int lane = tid & 63;
    const int nd   = *ndp;

    const float2* e2 = (const float2*)emb2;
    for (int i = tid; i < MAXD; i += 256) s_e[i] = e2[i];

    int   cs = 0, ce = INT_MAX;
    float c0 = 0.f, c1 = 0.f;
    {
        int ci = blockIdx.x * 256 + tid;
        if (ci < MCv){
            int4 r = csorted[ci];
            cs = r.x; ce = r.y;
            const float2 sc = *reinterpret_cast<const float2*>(&sc_c[2*r.z]);
            c0 = sc.x; c1 = sc.y;
        }
    }
    int ceprev = __shfl_up(ce, 1);
    const bool head = (lane == 0) || (ceprev != ce);
    bool okk[6];
    #pragma unroll
    for (int k = 0; k < 6; ++k) okk[k] = (__shfl_down(ce, 1 << k) == ce);

    for (int cb = blockIdx.y; cb * CHK < MDv; cb += DCH){
        const int dbase = cb * CHK;
        const int n = min(CHK, MDv - dbase);
        __syncthreads();   // protect s_d from previous chunk's readers
        for (int i = tid; i < n; i += 256){
            int4 r = dsorted[dbase + i];
            const float2 sd = *reinterpret_cast<const float2*>(&sc_d[2*r.z]);
            s_d[i] = make_int4(r.x, r.y, __float_as_int(sd.x), __float_as_int(sd.y));
        }
        __syncthreads();

        int   cur_de = s_d[0].y;
        float s0 = -INFINITY, s1 = -INFINITY;
        #pragma unroll 2
        for (int j = 0; j < n; ++j){
            int4 dj = s_d[j];                 // broadcast b128
            if (dj.y != cur_de){              // uniform branch
                flush_run(s0, s1, ce, cur_de, nd, head, okk, gent);
                cur_de = dj.y; s0 = -INFINITY; s1 = -INFINITY;
            }
            int dd = cs - dj.x; dd = dd < 0 ? -dd : dd;
            dd = dd < (MAXD-1) ? dd : (MAXD-1);
            float2 e = s_e[dd];               // gather b64
            s0 = fmaxf(s0, c0 + __int_as_float(dj.z) + e.x);
            s1 = fmaxf(s1, c1 + __int_as_float(dj.w) + e.y);
        }
        flush_run(s0, s1, ce, cur_de, nd, head, okk, gent);
    }
}

__global__ void softmax_kernel(const unsigned* __restrict__ gent,
                               float* __restrict__ out, int npairs){
    int p = blockIdx.x * blockDim.x + threadIdx.x;
    if (p < npairs){
        float a = dec_f(gent[p*2 + 0]);
        float b = dec_f(gent[p*2 + 1]);
        float m = fmaxf(a, b);
        float ea = expf(a - m), eb = expf(b - m);
        float inv = 1.f / (ea + eb);
        out[p*2 + 0] = ea * inv;
        out[p*2 + 1] = eb * inv;
    }
}

extern "C" void kernel_launch(void* const* d_in, const int* in_sizes, int n_in,
                              void* d_out, int out_size, void* d_ws, size_t ws_size,
                              hipStream_t stream)
{
    const float* h      = (const float*)d_in[0];
    const int*   cspans = (const int*)  d_in[1];
    const int*   centp  = (const int*)  d_in[2];
    const int*   dspans = (const int*)  d_in[3];
    const int*   dentp  = (const int*)  d_in[4];
    const float* Wc     = (const float*)d_in[5];
    const float* bc     = (const float*)d_in[6];
    const float* Wd     = (const float*)d_in[7];
    const float* bd     = (const float*)d_in[8];
    const float* Wemb   = (const float*)d_in[9];
    const float* Ws     = (const float*)d_in[10];
    const float* bs     = (const float*)d_in[11];
    const int*   ncp    = (const int*)  d_in[12];
    const int*   ndp    = (const int*)  d_in[13];

    const int MCv    = in_sizes[1] / 2;
    const int MDv    = in_sizes[3] / 2;
    const int npairs = out_size / 2;

    const int mtc = (MCv + 15) / 16;
    const int mtd = (MDv + 15) / 16;

    // ws layout (4B units): emb2[1280] | sc_c[2MC] | sc_d[2MD] | gent[out_size]
    //   | csorted[4MC] | dsorted[4MD] | Wt (ushort 2*112*512) | ghist
    float*    wsf    = (float*)d_ws;
    float*    emb2   = wsf;
    float*    sc_c   = wsf + 1280;
    float*    sc_d   = sc_c + (size_t)MCv * 2;
    unsigned* gent   = (unsigned*)(sc_d + (size_t)MDv * 2);
    int4*     csorted= (int4*)(gent + out_size);
    int4*     dsorted= csorted + MCv;
    unsigned short* Wt = (unsigned short*)(dsorted + MDv);
    int*      ghist  = (int*)(Wt + 2 * NPAD * H_DIM);

    const int gb    = (out_size + 255) / 256;
    const int eb    = (MAXD + 255) / 256;
    const int wb    = (2*NPAD*H_DIM + 4095) / 4096;
    const int off_e = 32 + gb;
    const int off_w = off_e + eb;

    hipLaunchKernelGGL(prep_kernel, dim3(off_w + wb), dim3(256), 0, stream,
                       Wemb, Ws, bs, Wc, Wd, centp, dentp, ncp, ndp,
                       emb2, gent, out_size, Wt, ghist,
                       MCv, MDv, off_e, off_w);

    hipLaunchKernelGGL(gemm_feat, dim3(mtc + mtd + 32), dim3(256), 0, stream,
                       h, Wt, bc, bd, Ws, sc_c, sc_d,
                       centp, dentp, ncp, ndp, cspans, dspans,
                       ghist, csorted, dsorted, mtc, mtd, MCv, MDv);

    hipLaunchKernelGGL(pair_kernel, dim3((MCv + 255)/256, DCH), dim3(256), 0, stream,
                       csorted, dsorted, sc_c, sc_d, emb2, ndp, gent, MCv, MDv);

    hipLaunchKernelGGL(softmax_kernel, dim3((npairs + 255)/256), dim3(256), 0, stream,
                       gent, (float*)d_out, npairs);
}

// Round 11
// 128.250 us; speedup vs baseline: 1.0551x; 1.0551x over previous
//
#include <hip/hip_runtime.h>
#include <math.h>
#include <limits.h>

// Fixed geometry from reference: T=8192, H=512, MC=MD=4096, N_ENT=128,
// MAX_DIST=600, feature dim 100 (padded to 112 for MFMA n-tiles).
// R11 = exact revert to R8 (best measured: 128.4 us). DCH=32 + unroll-2
// experiment (R10) measured -7 us regression; reverted.
#define H_DIM  512
#define NFEAT  100
#define NPAD   112
#define NT     7      // NPAD/16 n-tiles
#define KW     4      // K-split waves in gemm_feat (each wave: 4 of 16 ks)
#define SROW   520    // padded LDS row stride (shorts): 1040B = odd*16B -> 2-way banks
#define MAXD   600
#define MAXE   2048   // sort fast-path entity-count limit
#define SB     16     // sort blocks per side (parallel counting sort)
#define CHK    64     // dis mentions per staged chunk in pair kernel
#define DCH    64     // grid.y = number of dis-chunk streams (R8 best config)

#define NEG_ENC 0x007FFFFFu  // enc_f(-inf)

typedef __attribute__((ext_vector_type(8))) short short8v;  // 8 bf16
typedef __attribute__((ext_vector_type(4))) float f32x4;

// Monotonic float->uint mapping so unsigned atomicMax == float max.
__device__ __forceinline__ unsigned enc_f(float f){
    unsigned u = __float_as_uint(f);
    return (u & 0x80000000u) ? ~u : (u | 0x80000000u);
}
__device__ __forceinline__ float dec_f(unsigned e){
    unsigned u = (e & 0x80000000u) ? (e ^ 0x80000000u) : ~e;
    return __uint_as_float(u);
}
__device__ __forceinline__ unsigned short f2bf(float f){  // round-nearest-even
    unsigned x = __float_as_uint(f);
    return (unsigned short)((x + 0x7fffu + ((x >> 16) & 1u)) >> 16);
}

// Fused prep, block roles by blockIdx.x:
//  [0, 32)            : per-chunk entity histograms -> ghist (16 blocks/side)
//  [32, off_e)        : gent init to -inf
//  [off_e, off_w)     : emb2[d] = Wemb[d,:]@Ws[200:250] + bs
//  [off_w, ...)       : Wt[side][n][k] = bf16(W_side[k][n])  (zero-pad n>=100)
__global__ __launch_bounds__(256) void prep_kernel(
    const float* __restrict__ Wemb, const float* __restrict__ Ws,
    const float* __restrict__ bs,
    const float* __restrict__ Wc,   const float* __restrict__ Wd,
    const int* __restrict__ cent, const int* __restrict__ dent,
    const int* __restrict__ ncp,  const int* __restrict__ ndp,
    float* __restrict__ emb2, unsigned* __restrict__ gent, int gent_n,
    unsigned short* __restrict__ Wt, int* __restrict__ ghist,
    int MCv, int MDv, int off_e, int off_w)
{
    const int tid = threadIdx.x;
    const int bid = blockIdx.x;

    if (bid < 32){
        __shared__ int hist[MAXE];
        const int side = bid >> 4;
        const int b    = bid & 15;
        const int ne   = side ? *ndp : *ncp;
        if (ne > MAXE) return;                 // fallback: no sort
        const int* ent = side ? dent : cent;
        const int  M   = side ? MDv : MCv;
        const int chunk = (M + SB - 1) / SB;
        const int i0 = b * chunk, i1 = min(M, i0 + chunk);
        for (int e = tid; e < ne; e += 256) hist[e] = 0;
        __syncthreads();
        for (int i = i0 + tid; i < i1; i += 256) atomicAdd(&hist[ent[i]], 1);
        __syncthreads();
        int* gh = ghist + (side*SB + b) * MAXE;
        for (int e = tid; e < ne; e += 256) gh[e] = hist[e];
    } else if (bid < off_e){
        int i = (bid - 32) * 256 + tid;
        if (i < gent_n) gent[i] = NEG_ENC;
    } else if (bid < off_w){
        int d = (bid - off_e) * 256 + tid;
        if (d < MAXD){
            float a0 = bs[0], a1 = bs[1];
            #pragma unroll 5
            for (int q = 0; q < 50; ++q){
                float w = Wemb[d*50 + q];
                a0 += w * Ws[(200+q)*2 + 0];
                a1 += w * Ws[(200+q)*2 + 1];
            }
            emb2[d*2 + 0] = a0;
            emb2[d*2 + 1] = a1;
        }
    } else {
        const int base = (bid - off_w) * 4096;
        #pragma unroll
        for (int ii = 0; ii < 16; ++ii){
            int e = base + tid + 256*ii;
            if (e < 2*NPAD*H_DIM){
                int side = e / (NPAD*H_DIM);
                int rem  = e - side*(NPAD*H_DIM);
                int n    = rem / H_DIM;
                int k    = rem - n*H_DIM;
                const float* W = side ? Wd : Wc;
                Wt[e] = (n < NFEAT) ? f2bf(W[k*NFEAT + n]) : (unsigned short)0;
            }
        }
    }
}

// Blocks [0, mtc+mtd): fused span-sum (h -> LDS, wave-uniform len switch) +
// MFMA GEMM (A from LDS, 4-way K-split) + feature epilogue -> sc[m,2].
// Blocks [mtc+mtd, +32): scatter phase of the parallel counting sort.
__global__ __launch_bounds__(256) void gemm_feat(
    const float* __restrict__ h,
    const unsigned short* __restrict__ Wt,
    const float* __restrict__ bc, const float* __restrict__ bd,
    const float* __restrict__ Ws,
    float* __restrict__ sc_c, float* __restrict__ sc_d,
    const int* __restrict__ cent, const int* __restrict__ dent,
    const int* __restrict__ ncp,  const int* __restrict__ ndp,
    const int* __restrict__ cspans, const int* __restrict__ dspans,
    const int* __restrict__ ghist,
    int4* __restrict__ csorted, int4* __restrict__ dsorted,
    int mtc, int mtd, int MCv, int MDv)
{
    // shared overlay: gemm role = S_lds(16640B) + s_acc(21504B) = 38144B
    //                 scatter role = s_tot(8192) + s_cur(8192) + s_wsum(16)
    __shared__ __align__(16) char smem[38160];
    unsigned short* S_lds = (unsigned short*)smem;
    float*          s_acc = (float*)(smem + 16640);   // [(w-1)*28 + nt*4+r][64]
    int*            s_tot = (int*)smem;
    int*            s_cur = (int*)(smem + 8192);
    int*            s_wsum= (int*)(smem + 16384);

    const int tid  = threadIdx.x;
    const int lane = tid & 63;
    const int w    = tid >> 6;
    const int bid  = blockIdx.x;

    if (bid >= mtc + mtd){
        // ---- scatter role ----
        const int sb   = bid - (mtc + mtd);   // 0..31
        const int side = sb >> 4;
        const int b    = sb & 15;
        const int ne   = side ? *ndp : *ncp;
        const int* ent = side ? dent : cent;
        const int* spans = side ? dspans : cspans;
        int4* out      = side ? dsorted : csorted;
        const int M    = side ? MDv : MCv;
        const int chunk = (M + SB - 1) / SB;
        const int i0 = b * chunk, i1 = min(M, i0 + chunk);

        if (ne <= MAXE){
            const int* gh = ghist + side*SB*MAXE;
            for (int e = tid; e < ne; e += 256){
                int pre = 0, tot = 0;
                #pragma unroll
                for (int bb = 0; bb < SB; ++bb){
                    int v = gh[bb*MAXE + e];
                    tot += v;
                    pre += (bb < b) ? v : 0;
                }
                s_tot[e] = tot;
                s_cur[e] = pre;
            }
            __syncthreads();
            const int per = (ne + 255) / 256;
            const int lo = min(tid*per, ne), hi = min(lo + per, ne);
            int sum = 0;
            for (int j = lo; j < hi; ++j) sum += s_tot[j];
            int x = sum;
            #pragma unroll
            for (int k = 1; k < 64; k <<= 1){
                int y = __shfl_up(x, k);
                if (lane >= k) x += y;
            }
            int excl = x - sum;
            if (lane == 63) s_wsum[w] = x;
            __syncthreads();
            for (int ww = 0; ww < w; ++ww) excl += s_wsum[ww];
            int run = excl;
            for (int j = lo; j < hi; ++j){
                s_cur[j] += run;
                run += s_tot[j];
            }
            __syncthreads();
            for (int i = i0 + tid; i < i1; i += 256){
                int e = ent[i];
                int pos = atomicAdd(&s_cur[e], 1);
                out[pos] = make_int4(spans[i*2], e, i, 0);
            }
        } else {
            for (int i = i0 + tid; i < i1; i += 256)
                out[i] = make_int4(spans[i*2], ent[i], i, 0);
        }
        return;
    }

    // ---- span-sum staging + GEMM + fused feature epilogue ----
    const int side = (bid >= mtc);
    const int mt   = side ? (bid - mtc) : bid;
    const int* spans = side ? dspans : cspans;
    const int  M     = side ? MDv : MCv;

    // stage 4 rows per wave; each row: 64 lanes x 8 floats, len+1 row loads.
    // len is wave-uniform (one row per wave) -> switch costs no divergence.
    #pragma unroll
    for (int rr = 0; rr < 4; ++rr){
        const int rloc = w*4 + rr;            // 0..15
        const int ml   = mt*16 + rloc;
        float A0=0.f,A1=0.f,A2=0.f,A3=0.f,A4=0.f,A5=0.f,A6=0.f,A7=0.f;
        if (ml < M){
            const int s   = spans[ml*2];
            const int len = spans[ml*2 + 1] - s;   // 0..7
            const float* hp = h + (size_t)s * H_DIM + lane*8;
#define RW(r) { const float4* p_ = (const float4*)(hp + (size_t)(r)*H_DIM); \
                float4 u0=p_[0], u1=p_[1]; \
                A0+=u0.x; A1+=u0.y; A2+=u0.z; A3+=u0.w; \
                A4+=u1.x; A5+=u1.y; A6+=u1.z; A7+=u1.w; }
            switch(len){
                case 7: RW(7);
                case 6: RW(6);
                case 5: RW(5);
                case 4: RW(4);
                case 3: RW(3);
                case 2: RW(2);
                case 1: RW(1);
                default: RW(0);
            }
#undef RW
        }
        union { unsigned short us[8]; uint4 v; } o;
        o.us[0]=f2bf(A0); o.us[1]=f2bf(A1); o.us[2]=f2bf(A2); o.us[3]=f2bf(A3);
        o.us[4]=f2bf(A4); o.us[5]=f2bf(A5); o.us[6]=f2bf(A6); o.us[7]=f2bf(A7);
        *reinterpret_cast<uint4*>(S_lds + rloc*SROW + lane*8) = o.v;
    }
    __syncthreads();

    const unsigned short* B = Wt + (size_t)side * NPAD * H_DIM
                                 + (size_t)(lane & 15) * H_DIM
                                 + (lane >> 4) * 8 + w * 4 * 32;
    const unsigned short* Al = S_lds + (lane & 15) * SROW
                                     + (lane >> 4) * 8 + w * 4 * 32;

    f32x4 acc[NT];
    #pragma unroll
    for (int nt = 0; nt < NT; ++nt) acc[nt] = (f32x4){0.f,0.f,0.f,0.f};

    #pragma unroll
    for (int ks = 0; ks < 4; ++ks){
        short8v a = *reinterpret_cast<const short8v*>(Al + ks*32);
        #pragma unroll
        for (int nt = 0; nt < NT; ++nt){
            short8v b = *reinterpret_cast<const short8v*>(B + (size_t)nt*16*H_DIM + ks*32);
            acc[nt] = __builtin_amdgcn_mfma_f32_16x16x32_bf16(a, b, acc[nt], 0, 0, 0);
        }
    }

    if (w > 0){
        #pragma unroll
        for (int nt = 0; nt < NT; ++nt)
            #pragma unroll
            for (int r = 0; r < 4; ++r)
                s_acc[((w-1)*28 + nt*4 + r)*64 + lane] = acc[nt][r];
    }
    __syncthreads();
    if (w == 0){
        #pragma unroll
        for (int nt = 0; nt < NT; ++nt)
            #pragma unroll
            for (int r = 0; r < 4; ++r)
                acc[nt][r] += s_acc[(nt*4+r)*64 + lane]
                            + s_acc[(28 + nt*4+r)*64 + lane]
                            + s_acc[(56 + nt*4+r)*64 + lane];

        const float* bvec = side ? bd : bc;
        const int    wsoff = side ? NFEAT : 0;
        const int    nb    = lane & 15;
        float bb[NT], w0[NT], w1[NT];
        #pragma unroll
        for (int nt = 0; nt < NT; ++nt){
            int n = nt*16 + nb;
            bool v = (n < NFEAT);
            bb[nt] = v ? bvec[n] : 0.f;
            w0[nt] = v ? Ws[(wsoff + n)*2 + 0] : 0.f;
            w1[nt] = v ? Ws[(wsoff + n)*2 + 1] : 0.f;
        }
        const int ml0 = mt*16 + (lane >> 4)*4;
        float* sc     = side ? sc_d : sc_c;
        #pragma unroll
        for (int r = 0; r < 4; ++r){
            float p0 = 0.f, p1 = 0.f;
            #pragma unroll
            for (int nt = 0; nt < NT; ++nt){
                float f = tanhf(acc[nt][r] + bb[nt]);
                p0 += f * w0[nt];
                p1 += f * w1[nt];
            }
            #pragma unroll
            for (int k = 1; k < 16; k <<= 1){
                p0 += __shfl_xor(p0, k);
                p1 += __shfl_xor(p1, k);
            }
            int ml = ml0 + r;
            if (nb == 0 && ml < M){
                sc[ml*2 + 0] = p0;
                sc[ml*2 + 1] = p1;
            }
        }
    }
}

// Segmented (by ce, contiguous after sort) suffix max-reduce + head atomics.
__device__ __forceinline__ void flush_run(
    float s0, float s1, int ce, int de, int nd, bool head,
    const bool okk[6], unsigned* __restrict__ gent)
{
    float a0 = s0, a1 = s1;
    #pragma unroll
    for (int k = 0; k < 6; ++k){
        float b0 = __shfl_down(a0, 1 << k);
        float b1 = __shfl_down(a1, 1 << k);
        if (okk[k]){ a0 = fmaxf(a0, b0); a1 = fmaxf(a1, b1); }
    }
    if (head && ce != INT_MAX){
        atomicMax(&gent[(ce*nd + de)*2 + 0], enc_f(a0));
        atomicMax(&gent[(ce*nd + de)*2 + 1], enc_f(a1));
    }
}

// 256 sorted chem mentions per block (one per lane); stream sorted dis
// mentions in staged chunks; per-lane running max per dis-entity run;
// boundary flush via wave-segmented reduce -> few global atomics.
// NOTE: no end-of-kernel fence/counter fusion — device-scope __threadfence()
// per block forced an L2 writeback per block on gfx950 (non-coherent per-XCD
// L2s) and regressed pair 42 -> 91 us in R7. The kernel boundary before
// softmax_kernel provides ordering for free.
__global__ __launch_bounds__(256) void pair_kernel(
    const int4* __restrict__ csorted, const int4* __restrict__ dsorted,
    const float* __restrict__ sc_c,   const float* __restrict__ sc_d,
    const float* __restrict__ emb2,   const int* __restrict__ ndp,
    unsigned* __restrict__ gent, int MCv, int MDv)
{
    __shared__ float2 s_e[MAXD];
    __shared__ int4   s_d[CHK];

    const int tid  = threadIdx.x;
    const int lane = tid & 63;
    const int nd   = *ndp;

    const float2* e2 = (const float2*)emb2;
    for (int i = tid; i < MAXD; i += 256) s_e[i] = e2[i];

    int   cs = 0, ce = INT_MAX;
    float c0 = 0.f, c1 = 0.f;
    {
        int ci = blockIdx.x * 256 + tid;
        if (ci < MCv){
            int4 r = csorted[ci];
            cs = r.x; ce = r.y;
            const float2 sc = *reinterpret_cast<const float2*>(&sc_c[2*r.z]);
            c0 = sc.x; c1 = sc.y;
        }
    }
    int ceprev = __shfl_up(ce, 1);
    const bool head = (lane == 0) || (ceprev != ce);
    bool okk[6];
    #pragma unroll
    for (int k = 0; k < 6; ++k) okk[k] = (__shfl_down(ce, 1 << k) == ce);

    for (int cb = blockIdx.y; cb * CHK < MDv; cb += DCH){
        const int dbase = cb * CHK;
        const int n = min(CHK, MDv - dbase);
        __syncthreads();   // protect s_d from previous chunk's readers
        for (int i = tid; i < n; i += 256){
            int4 r = dsorted[dbase + i];
            const float2 sd = *reinterpret_cast<const float2*>(&sc_d[2*r.z]);
            s_d[i] = make_int4(r.x, r.y, __float_as_int(sd.x), __float_as_int(sd.y));
        }
        __syncthreads();

        int   cur_de = s_d[0].y;
        float s0 = -INFINITY, s1 = -INFINITY;
        for (int j = 0; j < n; ++j){
            int4 dj = s_d[j];                 // broadcast b128
            if (dj.y != cur_de){              // uniform branch
                flush_run(s0, s1, ce, cur_de, nd, head, okk, gent);
                cur_de = dj.y; s0 = -INFINITY; s1 = -INFINITY;
            }
            int dd = cs - dj.x; dd = dd < 0 ? -dd : dd;
            dd = dd < (MAXD-1) ? dd : (MAXD-1);
            float2 e = s_e[dd];               // gather b64
            s0 = fmaxf(s0, c0 + __int_as_float(dj.z) + e.x);
            s1 = fmaxf(s1, c1 + __int_as_float(dj.w) + e.y);
        }
        flush_run(s0, s1, ce, cur_de, nd, head, okk, gent);
    }
}

__global__ void softmax_kernel(const unsigned* __restrict__ gent,
                               float* __restrict__ out, int npairs){
    int p = blockIdx.x * blockDim.x + threadIdx.x;
    if (p < npairs){
        float a = dec_f(gent[p*2 + 0]);
        float b = dec_f(gent[p*2 + 1]);
        float m = fmaxf(a, b);
        float ea = expf(a - m), eb = expf(b - m);
        float inv = 1.f / (ea + eb);
        out[p*2 + 0] = ea * inv;
        out[p*2 + 1] = eb * inv;
    }
}

extern "C" void kernel_launch(void* const* d_in, const int* in_sizes, int n_in,
                              void* d_out, int out_size, void* d_ws, size_t ws_size,
                              hipStream_t stream)
{
    const float* h      = (const float*)d_in[0];
    const int*   cspans = (const int*)  d_in[1];
    const int*   centp  = (const int*)  d_in[2];
    const int*   dspans = (const int*)  d_in[3];
    const int*   dentp  = (const int*)  d_in[4];
    const float* Wc     = (const float*)d_in[5];
    const float* bc     = (const float*)d_in[6];
    const float* Wd     = (const float*)d_in[7];
    const float* bd     = (const float*)d_in[8];
    const float* Wemb   = (const float*)d_in[9];
    const float* Ws     = (const float*)d_in[10];
    const float* bs     = (const float*)d_in[11];
    const int*   ncp    = (const int*)  d_in[12];
    const int*   ndp    = (const int*)  d_in[13];

    const int MCv    = in_sizes[1] / 2;
    const int MDv    = in_sizes[3] / 2;
    const int npairs = out_size / 2;

    const int mtc = (MCv + 15) / 16;
    const int mtd = (MDv + 15) / 16;

    // ws layout (4B units): emb2[1280] | sc_c[2MC] | sc_d[2MD] | gent[out_size]
    //   | csorted[4MC] | dsorted[4MD] | Wt (ushort 2*112*512) | ghist
    float*    wsf    = (float*)d_ws;
    float*    emb2   = wsf;
    float*    sc_c   = wsf + 1280;
    float*    sc_d   = sc_c + (size_t)MCv * 2;
    unsigned* gent   = (unsigned*)(sc_d + (size_t)MDv * 2);
    int4*     csorted= (int4*)(gent + out_size);
    int4*     dsorted= csorted + MCv;
    unsigned short* Wt = (unsigned short*)(dsorted + MDv);
    int*      ghist  = (int*)(Wt + 2 * NPAD * H_DIM);

    const int gb    = (out_size + 255) / 256;
    const int eb    = (MAXD + 255) / 256;
    const int wb    = (2*NPAD*H_DIM + 4095) / 4096;
    const int off_e = 32 + gb;
    const int off_w = off_e + eb;

    hipLaunchKernelGGL(prep_kernel, dim3(off_w + wb), dim3(256), 0, stream,
                       Wemb, Ws, bs, Wc, Wd, centp, dentp, ncp, ndp,
                       emb2, gent, out_size, Wt, ghist,
                       MCv, MDv, off_e, off_w);

    hipLaunchKernelGGL(gemm_feat, dim3(mtc + mtd + 32), dim3(256), 0, stream,
                       h, Wt, bc, bd, Ws, sc_c, sc_d,
                       centp, dentp, ncp, ndp, cspans, dspans,
                       ghist, csorted, dsorted, mtc, mtd, MCv, MDv);

    hipLaunchKernelGGL(pair_kernel, dim3((MCv + 255)/256, DCH), dim3(256), 0, stream,
                       csorted, dsorted, sc_c, sc_d, emb2, ndp, gent, MCv, MDv);

    hipLaunchKernelGGL(softmax_kernel, dim3((npairs + 255)/256), dim3(256), 0, stream,
                       gent, (float*)d_out, npairs);
}